// Round 9
// baseline (6065.163 us; speedup 1.0000x reference)
//
#include <hip/hip_runtime.h>
#include <hip/hip_fp16.h>
#include <math.h>

// RETAIN layer: B=256, T=512, D=128. fp32 compute, f16 h-state storage.
// retain_gru_q: 512 blocks x 384 threads (6 waves), 2 blocks/CU co-resident.
//   Empirical (r2/r4/r8): per-step cost is barrier-latency-bound and grows with
//   waves-per-barrier-group (12w=1428us, 8w=824us, 12w=958us) vs ~770cyc VALU
//   floor. Fix: 6-wave groups + a SECOND independent block per CU to fill the
//   stalls (m114: co-resident waves' pipes overlap, time~max not sum).
//   Jobs (g,b) handed out longest-first via atomicAdd queue -> co-resident
//   blocks grab the two g's of the same b (equal length) -> overlap to the end.
//   Thread owns 8 consecutive cols x 32 rows (256 weight floats; AGPR-parked is
//   free - r8 showed VALUBusy contains no accvgpr tax). Combiner + e-pipeline
//   + lgkm-only end barrier kept verbatim from v3.
// Queue counter lives in d_out[0] (memset 0 -> gru bumps it -> memset 0 again
// -> attn atomicAdds) so ws keeps the exact r8 footprint (hB f16 + e f32).
// retain_attn_h: unchanged (measured ~130us).

#define BATCH 256
#define TLEN  512
#define DDIM  128
#define G3    384
#define NJOBS 512

static const size_t HB_SZ = (size_t)BATCH * TLEN * DDIM;  // f16 elems
static const size_t E_SZ  = (size_t)BATCH * TLEN;         // f32 elems

__device__ __forceinline__ int clamp_len(int l) {
    return l < 1 ? 1 : (l > TLEN ? TLEN : l);
}
__device__ __forceinline__ float sigm_f(float s) {
    s = fminf(fmaxf(s, -30.f), 30.f);
    return __fdividef(1.f, 1.f + __expf(-s));
}
__device__ __forceinline__ float tanh_f(float u) {
    u = fminf(fmaxf(u, -15.f), 15.f);
    const float e2 = __expf(2.f * u);
    return __fdividef(e2 - 1.f, e2 + 1.f);
}

// ---------------- queued fused GRU, 6-wave blocks, 2/CU ----------------
__global__ __launch_bounds__(384, 3) void retain_gru_q(
    const float* __restrict__ x, const int* __restrict__ lengths,
    const float* __restrict__ Wa, const float* __restrict__ Ua,
    const float* __restrict__ ba_in, const float* __restrict__ ba_rec,
    const float* __restrict__ Wb, const float* __restrict__ Ub,
    const float* __restrict__ bb_in, const float* __restrict__ bb_rec,
    const float* __restrict__ W_alpha, const float* __restrict__ b_alpha,
    __half* __restrict__ hB, float* __restrict__ e, int* __restrict__ cnt)
{
    const int tid = threadIdx.x;
    const int m   = (tid >= 192) ? 1 : 0;     // 0: X-side (W), 1: U-side (wave-uniform)
    const int tp  = tid - 192 * m;            // 0..191
    const int q   = tp / 48;                  // row quarter 0..3 (wave-uniform-ish)
    const int c8  = (tp % 48) * 8;            // output col base 0..376

    __shared__ int lensh[BATCH];
    __shared__ int rank2b[BATCH];
    __shared__ int jobsh;
    __shared__ __align__(16) float xsh[2][DDIM];
    __shared__ __align__(16) float hsh[2][DDIM];
    __shared__ __align__(16) float parts[2][4][G3];
    __shared__ __align__(16) float walsh[DDIM];
    __shared__ __align__(16) float ep8[2][8];

    if (tid < BATCH) lensh[tid] = clamp_len(lengths[tid]);
    if (tid < DDIM)  walsh[tid] = W_alpha[tid];
    __syncthreads();
    if (tid < BATCH) {                        // stable descending rank-sort
        const int myl = lensh[tid];
        int rank = 0;
        for (int j = 0; j < BATCH; ++j) {
            const int lj = lensh[j];
            rank += (lj > myl) || (lj == myl && j < tid);
        }
        rank2b[rank] = tid;
    }
    float balv = 0.f;
    if (tid == 136) balv = b_alpha[0];
    __syncthreads();                          // rank2b ready

    for (;;) {
        if (tid == 0) jobsh = atomicAdd(cnt, 1);
        __syncthreads();
        const int n = jobsh;
        if (n >= NJOBS) break;
        const int g   = n & 1;                // same b handed to 2 consecutive grabs
        const int b   = rank2b[n >> 1];       // longest-first
        const int len = lensh[b];

        // ---- weights for this job: 8 consecutive cols x 32 rows ----
        const float* __restrict__ Mw = m ? (g ? Ub : Ua) : (g ? Wb : Wa);
        float W0[32], W1[32], W2[32], W3[32], W4[32], W5[32], W6[32], W7[32];
        #pragma unroll
        for (int r = 0; r < 32; ++r) {
            const float* row = Mw + (size_t)(q * 32 + r) * G3 + c8;
            const float4 wa = *reinterpret_cast<const float4*>(row);
            const float4 wb = *reinterpret_cast<const float4*>(row + 4);
            W0[r] = wa.x; W1[r] = wa.y; W2[r] = wa.z; W3[r] = wa.w;
            W4[r] = wb.x; W5[r] = wb.y; W6[r] = wb.z; W7[r] = wb.w;
        }
        float bi0 = 0, bi1 = 0, bi2 = 0, br0 = 0, br1 = 0, br2 = 0;
        if (tid < DDIM) {
            const float* bi = g ? bb_in  : ba_in;
            const float* br = g ? bb_rec : ba_rec;
            bi0 = bi[tid]; bi1 = bi[tid + 128]; bi2 = bi[tid + 256];
            br0 = br[tid]; br1 = br[tid + 128]; br2 = br[tid + 256];
        }

        if (tid < DDIM) {
            hsh[1][tid] = 0.f;                // h_{-1}
            xsh[0][tid] = x[((size_t)b * TLEN + (len - 1)) * DDIM + tid];
        }
        __syncthreads();

        for (int t = 0; t < len; ++t) {
            float xnext = 0.f;
            if (tid < DDIM) {                 // prefetch next reversed row
                int rn = len - 2 - t; if (rn < 0) rn = 0;
                xnext = x[((size_t)b * TLEN + rn) * DDIM + tid];
            }
            // quarter matvec: 256 FMAs, 8 b128 broadcast reads
            const float* __restrict__ vh = (m ? hsh[(t + 1) & 1] : xsh[t & 1]) + q * 32;
            float A0 = 0.f, A1 = 0.f, A2 = 0.f, A3 = 0.f;
            float A4 = 0.f, A5 = 0.f, A6 = 0.f, A7 = 0.f;
            #pragma unroll
            for (int rr = 0; rr < 32; rr += 4) {
                const float4 v = *reinterpret_cast<const float4*>(vh + rr);
                A0 = fmaf(v.x, W0[rr+0], A0); A1 = fmaf(v.x, W1[rr+0], A1);
                A2 = fmaf(v.x, W2[rr+0], A2); A3 = fmaf(v.x, W3[rr+0], A3);
                A4 = fmaf(v.x, W4[rr+0], A4); A5 = fmaf(v.x, W5[rr+0], A5);
                A6 = fmaf(v.x, W6[rr+0], A6); A7 = fmaf(v.x, W7[rr+0], A7);
                A0 = fmaf(v.y, W0[rr+1], A0); A1 = fmaf(v.y, W1[rr+1], A1);
                A2 = fmaf(v.y, W2[rr+1], A2); A3 = fmaf(v.y, W3[rr+1], A3);
                A4 = fmaf(v.y, W4[rr+1], A4); A5 = fmaf(v.y, W5[rr+1], A5);
                A6 = fmaf(v.y, W6[rr+1], A6); A7 = fmaf(v.y, W7[rr+1], A7);
                A0 = fmaf(v.z, W0[rr+2], A0); A1 = fmaf(v.z, W1[rr+2], A1);
                A2 = fmaf(v.z, W2[rr+2], A2); A3 = fmaf(v.z, W3[rr+2], A3);
                A4 = fmaf(v.z, W4[rr+2], A4); A5 = fmaf(v.z, W5[rr+2], A5);
                A6 = fmaf(v.z, W6[rr+2], A6); A7 = fmaf(v.z, W7[rr+2], A7);
                A0 = fmaf(v.w, W0[rr+3], A0); A1 = fmaf(v.w, W1[rr+3], A1);
                A2 = fmaf(v.w, W2[rr+3], A2); A3 = fmaf(v.w, W3[rr+3], A3);
                A4 = fmaf(v.w, W4[rr+3], A4); A5 = fmaf(v.w, W5[rr+3], A5);
                A6 = fmaf(v.w, W6[rr+3], A6); A7 = fmaf(v.w, W7[rr+3], A7);
            }
            *reinterpret_cast<float4*>(&parts[m][q][c8])     = float4{A0, A1, A2, A3};
            *reinterpret_cast<float4*>(&parts[m][q][c8 + 4]) = float4{A4, A5, A6, A7};
            __syncthreads();                  // bar1 (x-prefetch lands under matvec)

            if (tid < DDIM) {                 // gate combiner (2 waves)
                const int d = tid;
                const float xz = bi0 + parts[0][0][d]     + parts[0][1][d]     + parts[0][2][d]     + parts[0][3][d];
                const float xr = bi1 + parts[0][0][128+d] + parts[0][1][128+d] + parts[0][2][128+d] + parts[0][3][128+d];
                const float xh = bi2 + parts[0][0][256+d] + parts[0][1][256+d] + parts[0][2][256+d] + parts[0][3][256+d];
                const float rz = br0 + parts[1][0][d]     + parts[1][1][d]     + parts[1][2][d]     + parts[1][3][d];
                const float rr_= br1 + parts[1][0][128+d] + parts[1][1][128+d] + parts[1][2][128+d] + parts[1][3][128+d];
                const float rh = br2 + parts[1][0][256+d] + parts[1][1][256+d] + parts[1][2][256+d] + parts[1][3][256+d];
                const float z  = sigm_f(xz + rz);
                const float r_ = sigm_f(xr + rr_);
                const float hh = tanh_f(xh + r_ * rh);
                const float hn = z * hsh[(t + 1) & 1][d] + (1.f - z) * hh;
                hsh[t & 1][d] = hn;
                xsh[(t + 1) & 1][d] = xnext;
                if (g) hB[((size_t)b * TLEN + t) * DDIM + d] = __float2half(hn);
            } else if (!g && tid >= 128 && tid < 136) {
                if (t >= 1) {                 // partials of e[t-1] = h_{t-1}.Walpha
                    const int k0 = (tid - 128) * 16;
                    const float* hp = hsh[(t + 1) & 1];
                    float s = 0.f;
                    #pragma unroll
                    for (int i2 = 0; i2 < 16; i2 += 4) {
                        const float4 hv = *reinterpret_cast<const float4*>(hp + k0 + i2);
                        const float4 wv = *reinterpret_cast<const float4*>(&walsh[k0 + i2]);
                        s = fmaf(hv.w, wv.w, fmaf(hv.z, wv.z, fmaf(hv.y, wv.y, fmaf(hv.x, wv.x, s))));
                    }
                    ep8[(t + 1) & 1][tid - 128] = s;
                }
            } else if (!g && tid == 136 && t >= 2) {   // finalize e[t-2]
                float s = balv;
                #pragma unroll
                for (int i2 = 0; i2 < 8; ++i2) s += ep8[t & 1][i2];
                e[(size_t)b * TLEN + (t - 2)] = s;
            }
            // raw barrier: wait LDS only; hB/e stores drain under next matvec
            asm volatile("s_waitcnt lgkmcnt(0)" ::: "memory");
            __builtin_amdgcn_s_barrier();
            __builtin_amdgcn_sched_barrier(0);
        }

        // e pipeline tails (g=0 only)
        if (!g && tid >= 128 && tid < 136) {  // partials of e[len-1]
            const int k0 = (tid - 128) * 16;
            const float* hp = hsh[(len + 1) & 1];
            float s = 0.f;
            #pragma unroll
            for (int i2 = 0; i2 < 16; i2 += 4) {
                const float4 hv = *reinterpret_cast<const float4*>(hp + k0 + i2);
                const float4 wv = *reinterpret_cast<const float4*>(&walsh[k0 + i2]);
                s = fmaf(hv.w, wv.w, fmaf(hv.z, wv.z, fmaf(hv.y, wv.y, fmaf(hv.x, wv.x, s))));
            }
            ep8[(len + 1) & 1][tid - 128] = s;
        } else if (!g && tid == 136 && len >= 2) {  // finalize e[len-2]
            float s = balv;
            #pragma unroll
            for (int i2 = 0; i2 < 8; ++i2) s += ep8[len & 1][i2];
            e[(size_t)b * TLEN + (len - 2)] = s;
        }
        __syncthreads();
        if (!g && tid == 136) {               // finalize e[len-1]
            float s = balv;
            #pragma unroll
            for (int i2 = 0; i2 < 8; ++i2) s += ep8[(len + 1) & 1][i2];
            e[(size_t)b * TLEN + (len - 1)] = s;
        }
        __syncthreads();                      // job boundary (protects jobsh reuse)
    }
}

// ---------------- attn: softmax(e) + tanh(h@Wbeta) + weighted sum ----------------
// grid = 1024 (4 blocks per b, t-split 128 each), block = 256 (d = tid&127, rh = tid>>7)
__global__ __launch_bounds__(256, 4) void retain_attn_h(
    const float* __restrict__ x, const int* __restrict__ lengths,
    const float* __restrict__ W_beta, const float* __restrict__ b_beta,
    const __half* __restrict__ hB, const float* __restrict__ eb,
    float* __restrict__ out)
{
    const int bid = blockIdx.x;
    const int b   = bid >> 2;
    const int tq  = bid & 3;
    const int len = clamp_len(lengths[b]);
    const float* __restrict__ e = eb + (size_t)b * TLEN;

    const int tid = threadIdx.x;
    const int d   = tid & 127;
    const int rh  = tid >> 7;

    float Wreg[64];
    #pragma unroll
    for (int rr = 0; rr < 64; rr++) Wreg[rr] = W_beta[(rh * 64 + rr) * DDIM + d];
    const float bb = b_beta[d];

    __shared__ float se[512];
    __shared__ float red[256];
    __shared__ __align__(16) float h2[2][128];
    __shared__ float part[2][2][128];

    for (int idx = tid; idx < 512; idx += 256) {
        const int tc = idx < len ? idx : len - 1;   // mask carry-forward
        se[idx] = e[tc];
    }
    __syncthreads();
    red[tid] = fmaxf(se[tid], se[tid + 256]);
    __syncthreads();
    for (int s = 128; s > 0; s >>= 1) {
        if (tid < s) red[tid] = fmaxf(red[tid], red[tid + s]);
        __syncthreads();
    }
    const float mx = red[0];
    __syncthreads();
    const float s0 = expf(se[tid] - mx), s1 = expf(se[tid + 256] - mx);
    se[tid] = s0; se[tid + 256] = s1;
    red[tid] = s0 + s1;
    __syncthreads();
    for (int s = 128; s > 0; s >>= 1) {
        if (tid < s) red[tid] += red[tid + s];
        __syncthreads();
    }
    const float inv = 1.f / red[0];
    __syncthreads();

    const int tbase = tq * 128;
    float acc = 0.f;
    for (int tp = 0; tp < 128; tp += 2) {
        const int t0 = tbase + tp;
        {
            const int t  = t0 + rh;
            const int tc = t < len ? t : len - 1;
            h2[rh][d] = __half2float(hB[((size_t)b * TLEN + tc) * DDIM + d]);
        }
        __syncthreads();
        float p0 = 0.f, p1 = 0.f;
        #pragma unroll
        for (int rr = 0; rr < 64; rr += 4) {
            const float4 ha = *reinterpret_cast<const float4*>(&h2[0][rh * 64 + rr]);
            const float4 hb = *reinterpret_cast<const float4*>(&h2[1][rh * 64 + rr]);
            p0 = fmaf(ha.x, Wreg[rr + 0], p0);
            p0 = fmaf(ha.y, Wreg[rr + 1], p0);
            p0 = fmaf(ha.z, Wreg[rr + 2], p0);
            p0 = fmaf(ha.w, Wreg[rr + 3], p0);
            p1 = fmaf(hb.x, Wreg[rr + 0], p1);
            p1 = fmaf(hb.y, Wreg[rr + 1], p1);
            p1 = fmaf(hb.z, Wreg[rr + 2], p1);
            p1 = fmaf(hb.w, Wreg[rr + 3], p1);
        }
        part[rh][0][d] = p0;
        part[rh][1][d] = p1;
        __syncthreads();
        if (rh == 0) {
            #pragma unroll
            for (int ti = 0; ti < 2; ti++) {
                const int t = t0 + ti;
                const float v  = tanhf(part[0][ti][d] + part[1][ti][d] + bb);
                const float al = se[t] * inv;
                const float xv = x[((size_t)b * TLEN + t) * DDIM + d];
                acc = fmaf(al * v, xv, acc);
            }
        }
        __syncthreads();
    }
    if (rh == 0) atomicAdd(&out[b * DDIM + d], acc);
}

extern "C" void kernel_launch(void* const* d_in, const int* in_sizes, int n_in,
                              void* d_out, int out_size, void* d_ws, size_t ws_size,
                              hipStream_t stream)
{
    const float* x       = (const float*)d_in[0];
    const int*   lengths = (const int*)  d_in[1];
    const float* Wa      = (const float*)d_in[2];
    const float* Ua      = (const float*)d_in[3];
    const float* ba_in   = (const float*)d_in[4];
    const float* ba_rec  = (const float*)d_in[5];
    const float* Wb      = (const float*)d_in[6];
    const float* Ub      = (const float*)d_in[7];
    const float* bb_in   = (const float*)d_in[8];
    const float* bb_rec  = (const float*)d_in[9];
    const float* W_alpha = (const float*)d_in[10];
    const float* b_alpha = (const float*)d_in[11];
    const float* W_beta  = (const float*)d_in[12];
    const float* b_beta  = (const float*)d_in[13];
    float* out = (float*)d_out;

    const size_t need = HB_SZ * sizeof(__half) + E_SZ * sizeof(float);  // ~34.1 MB
    if (ws_size < need) return;

    __half* hB  = (__half*)d_ws;
    float*  e   = (float*)((char*)d_ws + HB_SZ * sizeof(__half));
    int*    cnt = (int*)d_out;            // job queue counter (re-zeroed below)

    hipMemsetAsync(d_out, 0, (size_t)out_size * sizeof(float), stream);
    retain_gru_q<<<512, 384, 0, stream>>>(
        x, lengths, Wa, Ua, ba_in, ba_rec, Wb, Ub, bb_in, bb_rec, W_alpha, b_alpha,
        hB, e, cnt);
    hipMemsetAsync(d_out, 0, (size_t)out_size * sizeof(float), stream);  // clear cnt
    retain_attn_h<<<1024, 256, 0, stream>>>(x, lengths, W_beta, b_beta, hB, e, out);
}

// Round 10
// 1168.434 us; speedup vs baseline: 5.1908x; 5.1908x over previous
//
#include <hip/hip_runtime.h>
#include <hip/hip_fp16.h>
#include <math.h>

// RETAIN layer: B=256, T=512, D=128.
// retain_gru_h2: 512 blocks x 512 threads (8 waves), 2 blocks/CU co-resident.
//   r9 lesson: 256 f32 weight floats/thread spilled to scratch (FETCH 13 GB).
//   Fix: f16 weights as 96 half2 VGPRs/thread (3 cols x 64 rows) + fdot2
//   (v_dot2_f32_f16, f32 accumulate). __launch_bounds__(512,4) -> 128-reg cap
//   -> 16 waves/CU -> two independent barrier groups per CU fill each other's
//   barrier stalls (m114). Recurrence state h kept f32 (no quantization
//   feedback); f16 only on matvec operands. One job (g,b) per block;
//   g=bid>>8 so bid n / n+256 (same length rank) co-reside per XCD mod-8
//   round-robin. Combiner + e-pipeline + lgkm-only barrier verbatim from r8.
// retain_attn_h: unchanged (measured ~130us).
// ws: hB [B][T][128] f16 (33.5 MB) + e [B][T] f32 (0.5 MB).

#define BATCH 256
#define TLEN  512
#define DDIM  128
#define G3    384

typedef _Float16 half2_t __attribute__((ext_vector_type(2)));

#if defined(__has_builtin) && __has_builtin(__builtin_amdgcn_fdot2)
#define FDOT2(a, b, c) __builtin_amdgcn_fdot2((a), (b), (c), false)
#else
#define FDOT2(a, b, c) fmaf((float)(a)[0], (float)(b)[0], fmaf((float)(a)[1], (float)(b)[1], (c)))
#endif

static const size_t HB_SZ = (size_t)BATCH * TLEN * DDIM;  // f16 elems
static const size_t E_SZ  = (size_t)BATCH * TLEN;         // f32 elems

__device__ __forceinline__ int clamp_len(int l) {
    return l < 1 ? 1 : (l > TLEN ? TLEN : l);
}
__device__ __forceinline__ float sigm_f(float s) {
    s = fminf(fmaxf(s, -30.f), 30.f);
    return __fdividef(1.f, 1.f + __expf(-s));
}
__device__ __forceinline__ float tanh_f(float u) {
    u = fminf(fmaxf(u, -15.f), 15.f);
    const float e2 = __expf(2.f * u);
    return __fdividef(e2 - 1.f, e2 + 1.f);
}

// ---------------- f16-weight fused GRU, 8-wave blocks, 2/CU ----------------
__global__ __launch_bounds__(512, 4) void retain_gru_h2(
    const float* __restrict__ x, const int* __restrict__ lengths,
    const float* __restrict__ Wa, const float* __restrict__ Ua,
    const float* __restrict__ ba_in, const float* __restrict__ ba_rec,
    const float* __restrict__ Wb, const float* __restrict__ Ub,
    const float* __restrict__ bb_in, const float* __restrict__ bb_rec,
    const float* __restrict__ W_alpha, const float* __restrict__ b_alpha,
    __half* __restrict__ hB, float* __restrict__ e)
{
    const int bid = blockIdx.x;
    const int g   = bid >> 8;                 // 0..1
    const int rk  = bid & 255;                // length rank
    const int tid = threadIdx.x;
    const int m   = (tid >= 256) ? 1 : 0;     // 0: X-side (W), 1: U-side
    const int tt  = tid & 255;
    const int half= tt >> 7;                  // 64-row half (wave-uniform)
    const int c   = tt & 127;                 // col base; cols c, c+128, c+256

    __shared__ int lensh[BATCH];
    __shared__ int rank2b[BATCH];
    __shared__ __align__(16) _Float16 xsh16[DDIM];
    __shared__ __align__(16) _Float16 hsh16[DDIM];
    __shared__ __align__(16) float hsh32[2][DDIM];
    __shared__ __align__(16) float parts[2][2][G3];
    __shared__ __align__(16) float walsh[DDIM];
    __shared__ __align__(16) float bxsh[G3];
    __shared__ __align__(16) float bush[G3];
    __shared__ __align__(16) float ep8[2][8];

    if (tid < BATCH) lensh[tid] = clamp_len(lengths[tid]);
    if (tid < DDIM)  walsh[tid] = W_alpha[tid];
    {   // biases to LDS (saves VGPRs on combiner threads)
        const float* bi = g ? bb_in  : ba_in;
        const float* br = g ? bb_rec : ba_rec;
        for (int i = tid; i < G3; i += 512) { bxsh[i] = bi[i]; bush[i] = br[i]; }
    }
    __syncthreads();
    if (tid < BATCH) {                        // stable descending rank-sort
        const int myl = lensh[tid];
        int rank = 0;
        for (int j = 0; j < BATCH; ++j) {
            const int lj = lensh[j];
            rank += (lj > myl) || (lj == myl && j < tid);
        }
        rank2b[rank] = tid;
    }
    float balv = 0.f;
    if (tid == 136) balv = b_alpha[0];
    __syncthreads();                          // rank2b ready

    const int b   = rank2b[rk];
    const int len = lensh[b];

    // ---- weights: 3 cols x 64 rows as 96 half2 regs ----
    const float* __restrict__ Mw = m ? (g ? Ub : Ua) : (g ? Wb : Wa);
    half2_t W0[32], W1[32], W2[32];
    #pragma unroll
    for (int j = 0; j < 32; ++j) {
        const float* r0 = Mw + (size_t)(half * 64 + 2 * j) * G3 + c;
        const float* r1 = r0 + G3;
        W0[j] = (half2_t){(_Float16)r0[0],   (_Float16)r1[0]};
        W1[j] = (half2_t){(_Float16)r0[128], (_Float16)r1[128]};
        W2[j] = (half2_t){(_Float16)r0[256], (_Float16)r1[256]};
    }

    if (tid < DDIM) {
        hsh32[1][tid] = 0.f;                  // h_{-1}
        hsh16[tid]    = (_Float16)0.f;
        xsh16[tid]    = (_Float16)x[((size_t)b * TLEN + (len - 1)) * DDIM + tid];
    }
    __syncthreads();

    for (int t = 0; t < len; ++t) {
        float xnext = 0.f;
        if (tid < DDIM) {                     // prefetch next reversed row
            int rn = len - 2 - t; if (rn < 0) rn = 0;
            xnext = x[((size_t)b * TLEN + rn) * DDIM + tid];
        }
        // matvec: 96 fdot2, 8 b128 broadcast reads (single-buffered f16 inputs:
        // read pre-bar1, written post-bar1 -> no race)
        const uint* __restrict__ vhu =
            reinterpret_cast<const uint*>(m ? hsh16 : xsh16) + half * 32;
        float A0 = 0.f, A1 = 0.f, A2 = 0.f;
        #pragma unroll
        for (int j = 0; j < 32; j += 4) {
            const uint4 v = *reinterpret_cast<const uint4*>(vhu + j);
            const half2_t p0 = __builtin_bit_cast(half2_t, v.x);
            const half2_t p1 = __builtin_bit_cast(half2_t, v.y);
            const half2_t p2 = __builtin_bit_cast(half2_t, v.z);
            const half2_t p3 = __builtin_bit_cast(half2_t, v.w);
            A0 = FDOT2(p0, W0[j+0], A0); A1 = FDOT2(p0, W1[j+0], A1); A2 = FDOT2(p0, W2[j+0], A2);
            A0 = FDOT2(p1, W0[j+1], A0); A1 = FDOT2(p1, W1[j+1], A1); A2 = FDOT2(p1, W2[j+1], A2);
            A0 = FDOT2(p2, W0[j+2], A0); A1 = FDOT2(p2, W1[j+2], A1); A2 = FDOT2(p2, W2[j+2], A2);
            A0 = FDOT2(p3, W0[j+3], A0); A1 = FDOT2(p3, W1[j+3], A1); A2 = FDOT2(p3, W2[j+3], A2);
        }
        parts[m][half][c]       = A0;
        parts[m][half][c + 128] = A1;
        parts[m][half][c + 256] = A2;
        __syncthreads();                      // bar1

        if (tid < DDIM) {                     // gate combiner (2 waves)
            const int d = tid;
            const float xz = bxsh[d]       + parts[0][0][d]       + parts[0][1][d];
            const float xr = bxsh[128 + d] + parts[0][0][128 + d] + parts[0][1][128 + d];
            const float xh = bxsh[256 + d] + parts[0][0][256 + d] + parts[0][1][256 + d];
            const float rz = bush[d]       + parts[1][0][d]       + parts[1][1][d];
            const float rr_= bush[128 + d] + parts[1][0][128 + d] + parts[1][1][128 + d];
            const float rh = bush[256 + d] + parts[1][0][256 + d] + parts[1][1][256 + d];
            const float z  = sigm_f(xz + rz);
            const float r_ = sigm_f(xr + rr_);
            const float hh = tanh_f(xh + r_ * rh);
            const float hn = z * hsh32[(t + 1) & 1][d] + (1.f - z) * hh;
            hsh32[t & 1][d] = hn;             // f32 state (e-pipeline reads prev buf)
            hsh16[d] = (_Float16)hn;          // f16 matvec copy
            xsh16[d] = (_Float16)xnext;
            if (g) hB[((size_t)b * TLEN + t) * DDIM + d] = __float2half(hn);
        } else if (!g && tid >= 128 && tid < 136) {
            if (t >= 1) {                     // partials of e[t-1] = h_{t-1}.Walpha
                const int k0 = (tid - 128) * 16;
                const float* hp = hsh32[(t + 1) & 1];
                float s = 0.f;
                #pragma unroll
                for (int i2 = 0; i2 < 16; i2 += 4) {
                    const float4 hv = *reinterpret_cast<const float4*>(hp + k0 + i2);
                    const float4 wv = *reinterpret_cast<const float4*>(&walsh[k0 + i2]);
                    s = fmaf(hv.w, wv.w, fmaf(hv.z, wv.z, fmaf(hv.y, wv.y, fmaf(hv.x, wv.x, s))));
                }
                ep8[(t + 1) & 1][tid - 128] = s;
            }
        } else if (!g && tid == 136 && t >= 2) {    // finalize e[t-2]
            float s = balv;
            #pragma unroll
            for (int i2 = 0; i2 < 8; ++i2) s += ep8[t & 1][i2];
            e[(size_t)b * TLEN + (t - 2)] = s;
        }
        // raw barrier: wait LDS only; hB/e stores drain under next matvec
        asm volatile("s_waitcnt lgkmcnt(0)" ::: "memory");
        __builtin_amdgcn_s_barrier();
        __builtin_amdgcn_sched_barrier(0);
    }

    // e pipeline tails (g=0 only)
    if (!g && tid >= 128 && tid < 136) {      // partials of e[len-1]
        const int k0 = (tid - 128) * 16;
        const float* hp = hsh32[(len + 1) & 1];
        float s = 0.f;
        #pragma unroll
        for (int i2 = 0; i2 < 16; i2 += 4) {
            const float4 hv = *reinterpret_cast<const float4*>(hp + k0 + i2);
            const float4 wv = *reinterpret_cast<const float4*>(&walsh[k0 + i2]);
            s = fmaf(hv.w, wv.w, fmaf(hv.z, wv.z, fmaf(hv.y, wv.y, fmaf(hv.x, wv.x, s))));
        }
        ep8[(len + 1) & 1][tid - 128] = s;
    } else if (!g && tid == 136 && len >= 2) {     // finalize e[len-2]
        float s = balv;
        #pragma unroll
        for (int i2 = 0; i2 < 8; ++i2) s += ep8[len & 1][i2];
        e[(size_t)b * TLEN + (len - 2)] = s;
    }
    __syncthreads();
    if (!g && tid == 136) {                   // finalize e[len-1]
        float s = balv;
        #pragma unroll
        for (int i2 = 0; i2 < 8; ++i2) s += ep8[(len + 1) & 1][i2];
        e[(size_t)b * TLEN + (len - 1)] = s;
    }
}

// ---------------- attn: softmax(e) + tanh(h@Wbeta) + weighted sum ----------------
// grid = 1024 (4 blocks per b, t-split 128 each), block = 256 (d = tid&127, rh = tid>>7)
__global__ __launch_bounds__(256, 4) void retain_attn_h(
    const float* __restrict__ x, const int* __restrict__ lengths,
    const float* __restrict__ W_beta, const float* __restrict__ b_beta,
    const __half* __restrict__ hB, const float* __restrict__ eb,
    float* __restrict__ out)
{
    const int bid = blockIdx.x;
    const int b   = bid >> 2;
    const int tq  = bid & 3;
    const int len = clamp_len(lengths[b]);
    const float* __restrict__ e = eb + (size_t)b * TLEN;

    const int tid = threadIdx.x;
    const int d   = tid & 127;
    const int rh  = tid >> 7;

    float Wreg[64];
    #pragma unroll
    for (int rr = 0; rr < 64; rr++) Wreg[rr] = W_beta[(rh * 64 + rr) * DDIM + d];
    const float bb = b_beta[d];

    __shared__ float se[512];
    __shared__ float red[256];
    __shared__ __align__(16) float h2[2][128];
    __shared__ float part[2][2][128];

    for (int idx = tid; idx < 512; idx += 256) {
        const int tc = idx < len ? idx : len - 1;   // mask carry-forward
        se[idx] = e[tc];
    }
    __syncthreads();
    red[tid] = fmaxf(se[tid], se[tid + 256]);
    __syncthreads();
    for (int s = 128; s > 0; s >>= 1) {
        if (tid < s) red[tid] = fmaxf(red[tid], red[tid + s]);
        __syncthreads();
    }
    const float mx = red[0];
    __syncthreads();
    const float s0 = expf(se[tid] - mx), s1 = expf(se[tid + 256] - mx);
    se[tid] = s0; se[tid + 256] = s1;
    red[tid] = s0 + s1;
    __syncthreads();
    for (int s = 128; s > 0; s >>= 1) {
        if (tid < s) red[tid] += red[tid + s];
        __syncthreads();
    }
    const float inv = 1.f / red[0];
    __syncthreads();

    const int tbase = tq * 128;
    float acc = 0.f;
    for (int tp = 0; tp < 128; tp += 2) {
        const int t0 = tbase + tp;
        {
            const int t  = t0 + rh;
            const int tc = t < len ? t : len - 1;
            h2[rh][d] = __half2float(hB[((size_t)b * TLEN + tc) * DDIM + d]);
        }
        __syncthreads();
        float p0 = 0.f, p1 = 0.f;
        #pragma unroll
        for (int rr = 0; rr < 64; rr += 4) {
            const float4 ha = *reinterpret_cast<const float4*>(&h2[0][rh * 64 + rr]);
            const float4 hb = *reinterpret_cast<const float4*>(&h2[1][rh * 64 + rr]);
            p0 = fmaf(ha.x, Wreg[rr + 0], p0);
            p0 = fmaf(ha.y, Wreg[rr + 1], p0);
            p0 = fmaf(ha.z, Wreg[rr + 2], p0);
            p0 = fmaf(ha.w, Wreg[rr + 3], p0);
            p1 = fmaf(hb.x, Wreg[rr + 0], p1);
            p1 = fmaf(hb.y, Wreg[rr + 1], p1);
            p1 = fmaf(hb.z, Wreg[rr + 2], p1);
            p1 = fmaf(hb.w, Wreg[rr + 3], p1);
        }
        part[rh][0][d] = p0;
        part[rh][1][d] = p1;
        __syncthreads();
        if (rh == 0) {
            #pragma unroll
            for (int ti = 0; ti < 2; ti++) {
                const int t = t0 + ti;
                const float v  = tanhf(part[0][ti][d] + part[1][ti][d] + bb);
                const float al = se[t] * inv;
                const float xv = x[((size_t)b * TLEN + t) * DDIM + d];
                acc = fmaf(al * v, xv, acc);
            }
        }
        __syncthreads();
    }
    if (rh == 0) atomicAdd(&out[b * DDIM + d], acc);
}

extern "C" void kernel_launch(void* const* d_in, const int* in_sizes, int n_in,
                              void* d_out, int out_size, void* d_ws, size_t ws_size,
                              hipStream_t stream)
{
    const float* x       = (const float*)d_in[0];
    const int*   lengths = (const int*)  d_in[1];
    const float* Wa      = (const float*)d_in[2];
    const float* Ua      = (const float*)d_in[3];
    const float* ba_in   = (const float*)d_in[4];
    const float* ba_rec  = (const float*)d_in[5];
    const float* Wb      = (const float*)d_in[6];
    const float* Ub      = (const float*)d_in[7];
    const float* bb_in   = (const float*)d_in[8];
    const float* bb_rec  = (const float*)d_in[9];
    const float* W_alpha = (const float*)d_in[10];
    const float* b_alpha = (const float*)d_in[11];
    const float* W_beta  = (const float*)d_in[12];
    const float* b_beta  = (const float*)d_in[13];
    float* out = (float*)d_out;

    const size_t need = HB_SZ * sizeof(__half) + E_SZ * sizeof(float);  // ~34.1 MB
    if (ws_size < need) return;

    __half* hB = (__half*)d_ws;
    float*  e  = (float*)((char*)d_ws + HB_SZ * sizeof(__half));

    hipMemsetAsync(d_out, 0, (size_t)out_size * sizeof(float), stream);
    retain_gru_h2<<<512, 512, 0, stream>>>(
        x, lengths, Wa, Ua, ba_in, ba_rec, Wb, Ub, bb_in, bb_rec, W_alpha, b_alpha, hB, e);
    retain_attn_h<<<1024, 256, 0, stream>>>(x, lengths, W_beta, b_beta, hB, e, out);
}